// Round 8
// baseline (224.726 us; speedup 1.0000x reference)
//
#include <hip/hip_runtime.h>
#include <math.h>

#define EPS 1e-8f
#define NBINS 4096
#define BIN_SHIFT 20    // 32 - log2(NBINS)
#define CAP 4096        // candidate buffer capacity (expected ~100-400 used)
#define NBLOCKS_A 2048  // 8 blocks/CU on 256 CUs

typedef float f4 __attribute__((ext_vector_type(4)));

// monotonic map: float -> u32 preserving order (no NaNs in this problem)
__device__ __forceinline__ unsigned mono(float v) {
    unsigned u = __float_as_uint(v);
    return (u & 0x80000000u) ? ~u : (u | 0x80000000u);
}
__device__ __forceinline__ float unmono(unsigned u) {
    return __uint_as_float((u & 0x80000000u) ? (u & 0x7FFFFFFFu) : ~u);
}

// 16-lane (DPP row) sum: ror8, ror4, quad xor2, quad xor1 — every lane gets its
// 16-group's sum. Pure VALU, no DS pipe.
__device__ __forceinline__ float rowsum16(float x) {
    x += __int_as_float(__builtin_amdgcn_update_dpp(0, __float_as_int(x), 0x128, 0xF, 0xF, true)); // row_ror:8
    x += __int_as_float(__builtin_amdgcn_update_dpp(0, __float_as_int(x), 0x124, 0xF, 0xF, true)); // row_ror:4
    x += __int_as_float(__builtin_amdgcn_update_dpp(0, __float_as_int(x), 0x04E, 0xF, 0xF, true)); // quad_perm xor2
    x += __int_as_float(__builtin_amdgcn_update_dpp(0, __float_as_int(x), 0x0B1, 0xF, 0xF, true)); // quad_perm xor1
    return x;
}

// full 64-lane sum; result valid in lanes 48..63 (writer uses lane 63).
// rowsum16 puts each 16-group's sum in all its lanes; row_bcast:15 then
// row_bcast:31 combine the 4 group sums (classic GCN tree, bound_ctrl=0-fill).
__device__ __forceinline__ float sum64(float x) {
    x = rowsum16(x);
    x += __int_as_float(__builtin_amdgcn_update_dpp(0, __float_as_int(x), 0x142, 0xF, 0xF, true)); // row_bcast:15
    x += __int_as_float(__builtin_amdgcn_update_dpp(0, __float_as_int(x), 0x143, 0xF, 0xF, true)); // row_bcast:31
    return x;
}

// ---- A: score all rows, write monotonic keys, build global histogram ----
// ONE ROW PER WAVE: lane l covers f4 column l -> each load instruction touches
// one contiguous 1 KB segment (the m13 6.29 TB/s copy pattern). 4-row unroll.
__global__ __launch_bounds__(256, 8) void score_hist_kernel(
    const f4* __restrict__ q4, const f4* __restrict__ emb,
    const float* __restrict__ rep, unsigned* __restrict__ keys_out,
    unsigned* __restrict__ ghist, int rows_per_block) {
    __shared__ unsigned hist[NBINS];
    __shared__ float boost[512];
    const int tid = threadIdx.x;
    for (int j = tid; j < NBINS; j += 256) hist[j] = 0;

    const int lane = tid & 63;
    const int w = tid >> 6;
    const int base = blockIdx.x * rows_per_block;

    // precompute reputation boost for this block's 512 rows (coalesced, all lanes)
    {
        const float r0 = rep[base + tid];
        const float r1 = rep[base + 256 + tid];
        boost[tid]       = 1.0f + 0.1f * tanhf(0.5f * r0);
        boost[tid + 256] = 1.0f + 0.1f * tanhf(0.5f * r1);
    }

    const f4 ql = q4[lane];   // lane's 4 query columns (4 VGPR total)
    float qsq = ql.x * ql.x + ql.y * ql.y + ql.z * ql.z + ql.w * ql.w;
    qsq = sum64(qsq);
    const float qn = fmaxf(sqrtf(qsq), EPS);   // valid in lanes 48..63 (writer = 63)

    __syncthreads();  // hist zeroed, boost ready

    const int iters = rows_per_block >> 4;  // 16 rows per block-iter (4 waves x 4 rows)
    for (int it = 0; it < iters; ++it) {
        const int rl = (it << 4) + (w << 2);          // first of this wave's 4 rows
        const f4* rp = emb + (size_t)(base + rl) * 64 + lane;
        f4 v[4];
#pragma unroll
        for (int u = 0; u < 4; ++u) v[u] = rp[u * 64];  // 4 x contiguous 1KB/wave

        float d[4], sq[4];
#pragma unroll
        for (int u = 0; u < 4; ++u) {
            d[u]  = v[u].x * ql.x + v[u].y * ql.y + v[u].z * ql.z + v[u].w * ql.w;
            sq[u] = v[u].x * v[u].x + v[u].y * v[u].y + v[u].z * v[u].z + v[u].w * v[u].w;
            d[u]  = sum64(d[u]);
            sq[u] = sum64(sq[u]);
        }
        if (lane == 63) {
#pragma unroll
            for (int u = 0; u < 4; ++u) {
                const float en = fmaxf(sqrtf(sq[u]), EPS);
                const unsigned key = mono((d[u] / (en * qn)) * boost[rl + u]);
                keys_out[base + rl + u] = key;
                atomicAdd(&hist[key >> BIN_SHIFT], 1u);
            }
        }
    }
    __syncthreads();
    for (int j = tid; j < NBINS; j += 256) {
        const unsigned h = hist[j];
        if (h) atomicAdd(&ghist[j], h);
    }
}

// ---- B: find largest bin b with suffix-count(b) >= k; threshold = b << BIN_SHIFT ----
__global__ __launch_bounds__(256) void scan_kernel(
    const unsigned* __restrict__ ghist, unsigned* __restrict__ thresh, int k) {
    __shared__ unsigned partial[256];
    __shared__ unsigned suffix[256];
    const int tid = threadIdx.x;
    unsigned bins[16];
    unsigned p = 0;
#pragma unroll
    for (int j = 0; j < 16; ++j) { bins[j] = ghist[tid * 16 + j]; p += bins[j]; }
    partial[tid] = p;
    __syncthreads();
    if (tid == 0) {
        unsigned run = 0;
        for (int t = 255; t >= 0; --t) { suffix[t] = run; run += partial[t]; }
    }
    __syncthreads();
    const unsigned above = suffix[tid];
    if (above < (unsigned)k && above + p >= (unsigned)k) {  // unique crossing chunk
        unsigned run = above;
        int b = tid * 16;
        for (int j = 15; j >= 0; --j) {
            run += bins[j];
            if (run >= (unsigned)k) { b = tid * 16 + j; break; }
        }
        thresh[0] = ((unsigned)b) << BIN_SHIFT;
    }
}

// ---- C: compact candidates >= threshold (order-invariant downstream) ----
__global__ __launch_bounds__(256) void compact_kernel(
    const unsigned* __restrict__ keys, const unsigned* __restrict__ thresh,
    unsigned* __restrict__ counter, unsigned long long* __restrict__ cand) {
    const unsigned T = thresh[0];
    const int i0 = (blockIdx.x * 256 + threadIdx.x) * 4;
    const uint4 kv = *(const uint4*)(keys + i0);
#pragma unroll
    for (int j = 0; j < 4; ++j) {
        const unsigned kj = j == 0 ? kv.x : j == 1 ? kv.y : j == 2 ? kv.z : kv.w;
        if (kj >= T) {
            const unsigned p = atomicAdd(counter, 1u);
            if (p < CAP)
                cand[p] = ((unsigned long long)kj << 32) |
                          (unsigned long long)(0xFFFFFFFFu - (unsigned)(i0 + j));
        }
    }
}

// ---- D: rank-based exact top-k (no serial loop) ----
// Keys unique -> ranks unique -> each of the k output slots written exactly once.
__global__ __launch_bounds__(256) void final_select_kernel(
    const unsigned long long* __restrict__ cand, const unsigned* __restrict__ counter,
    float* __restrict__ out, int k) {
    __shared__ unsigned long long skeys[CAP];
    const int tid = threadIdx.x;
    const int count = min((int)counter[0], CAP);
    for (int j = tid; j < count; j += 256) skeys[j] = cand[j];
    __syncthreads();
    for (int j = tid; j < count; j += 256) {
        const unsigned long long kj = skeys[j];
        int r = 0;
        for (int i = 0; i < count; ++i) r += (skeys[i] > kj);  // broadcast LDS reads
        if (r < k) {
            out[r]     = unmono((unsigned)(kj >> 32));
            out[k + r] = (float)(0xFFFFFFFFu - (unsigned)(kj & 0xFFFFFFFFu));
        }
    }
}

extern "C" void kernel_launch(void* const* d_in, const int* in_sizes, int n_in,
                              void* d_out, int out_size, void* d_ws, size_t ws_size,
                              hipStream_t stream) {
    const float* q   = (const float*)d_in[0];   // [256]
    const float* emb = (const float*)d_in[1];   // [N,256]
    const float* rep = (const float*)d_in[2];   // [N]
    const int N = in_sizes[2];                  // 1048576
    const int k = out_size / 2;                 // 64

    // ws layout: keys u32[N] | ghist u32[NBINS] | thresh u32 | counter u32 | cand u64[CAP]
    unsigned* keys    = (unsigned*)d_ws;
    unsigned* ghist   = keys + N;
    unsigned* thresh  = ghist + NBINS;
    unsigned* counter = thresh + 1;
    unsigned long long* cand = (unsigned long long*)(counter + 1);  // 8B-aligned

    // zero histogram + threshold + counter each call (ws not re-poisoned between replays)
    (void)hipMemsetAsync(ghist, 0, (NBINS + 2) * sizeof(unsigned), stream);

    score_hist_kernel<<<NBLOCKS_A, 256, 0, stream>>>(
        (const f4*)q, (const f4*)emb, rep, keys, ghist, N / NBLOCKS_A);
    scan_kernel<<<1, 256, 0, stream>>>(ghist, thresh, k);
    compact_kernel<<<N / 1024, 256, 0, stream>>>(keys, thresh, counter, cand);
    final_select_kernel<<<1, 256, 0, stream>>>(cand, counter, (float*)d_out, k);
}

// Round 9
// 197.903 us; speedup vs baseline: 1.1355x; 1.1355x over previous
//
#include <hip/hip_runtime.h>
#include <math.h>

#define EPS 1e-8f
#define NBINS 4096
#define BIN_SHIFT 20    // 32 - log2(NBINS)
#define CAP 4096        // candidate buffer capacity (expected ~100-400 used)
#define NBLOCKS_A 2048  // 8 blocks/CU on 256 CUs

typedef float f4 __attribute__((ext_vector_type(4)));

// monotonic map: float -> u32 preserving order (no NaNs in this problem)
__device__ __forceinline__ unsigned mono(float v) {
    unsigned u = __float_as_uint(v);
    return (u & 0x80000000u) ? ~u : (u | 0x80000000u);
}
__device__ __forceinline__ float unmono(unsigned u) {
    return __uint_as_float((u & 0x80000000u) ? (u & 0x7FFFFFFFu) : ~u);
}

// 16-lane (DPP row) sum: ror8, ror4, quad xor2, quad xor1 — pure VALU, no DS pipe.
// Addend tree at lane (c==0) identical to __shfl_xor(8,4,2,1); verified absmax 0.0.
__device__ __forceinline__ float rowsum16(float x) {
    x += __int_as_float(__builtin_amdgcn_update_dpp(0, __float_as_int(x), 0x128, 0xF, 0xF, true)); // row_ror:8
    x += __int_as_float(__builtin_amdgcn_update_dpp(0, __float_as_int(x), 0x124, 0xF, 0xF, true)); // row_ror:4
    x += __int_as_float(__builtin_amdgcn_update_dpp(0, __float_as_int(x), 0x04E, 0xF, 0xF, true)); // quad_perm xor2
    x += __int_as_float(__builtin_amdgcn_update_dpp(0, __float_as_int(x), 0x0B1, 0xF, 0xF, true)); // quad_perm xor1
    return x;
}

// ---- A: score all rows, write monotonic keys, build global histogram ----
// R6 structure (best: 218.3us). SINGLE CHANGE vs R6: emb loads are nontemporal
// (no-allocate) — zero-reuse 1GB stream should skip L2/L3 fill churn.
// NO __threadfence anywhere (R4's 2.5x regression is attributed to the fences).
__global__ __launch_bounds__(256, 8) void score_hist_kernel(
    const f4* __restrict__ q4, const f4* __restrict__ emb,
    const float* __restrict__ rep, unsigned* __restrict__ keys_out,
    unsigned* __restrict__ ghist, int rows_per_block) {
    __shared__ unsigned hist[NBINS];
    __shared__ float boost[512];
    const int tid = threadIdx.x;
    for (int j = tid; j < NBINS; j += 256) hist[j] = 0;

    const int lane = tid & 63;
    const int w = tid >> 6;
    const int c = lane & 15;    // column group within row
    const int sub = lane >> 4;  // which of the wave's 4 rows
    const int base = blockIdx.x * rows_per_block;

    // precompute reputation boost for this block's 512 rows (coalesced, all lanes)
    {
        const float r0 = rep[base + tid];
        const float r1 = rep[base + 256 + tid];
        boost[tid]       = 1.0f + 0.1f * tanhf(0.5f * r0);
        boost[tid + 256] = 1.0f + 0.1f * tanhf(0.5f * r1);
    }

    f4 ql[4];
    float qsq = 0.f;
#pragma unroll
    for (int j = 0; j < 4; ++j) {
        ql[j] = q4[c + 16 * j];
        qsq += ql[j].x * ql[j].x + ql[j].y * ql[j].y + ql[j].z * ql[j].z + ql[j].w * ql[j].w;
    }
    qsq = rowsum16(qsq);
    const float qn = fmaxf(sqrtf(qsq), EPS);

    __syncthreads();  // hist zeroed, boost ready

    const int iters = rows_per_block >> 5;  // 32 rows per block-iteration (2x unroll)
    for (int it = 0; it < iters; ++it) {
        const int rl0 = (it << 5) + (w << 2) + sub;
        const int rl1 = rl0 + 16;
        const f4* rp0 = emb + (size_t)(base + rl0) * 64 + c;
        const f4* rp1 = emb + (size_t)(base + rl1) * 64 + c;
        f4 v0[4], v1[4];
#pragma unroll
        for (int j = 0; j < 4; ++j) v0[j] = __builtin_nontemporal_load(rp0 + 16 * j);
#pragma unroll
        for (int j = 0; j < 4; ++j) v1[j] = __builtin_nontemporal_load(rp1 + 16 * j);

        float d0 = 0.f, sq0 = 0.f, d1 = 0.f, sq1 = 0.f;
#pragma unroll
        for (int j = 0; j < 4; ++j) {
            d0  += v0[j].x * ql[j].x + v0[j].y * ql[j].y + v0[j].z * ql[j].z + v0[j].w * ql[j].w;
            sq0 += v0[j].x * v0[j].x + v0[j].y * v0[j].y + v0[j].z * v0[j].z + v0[j].w * v0[j].w;
        }
#pragma unroll
        for (int j = 0; j < 4; ++j) {
            d1  += v1[j].x * ql[j].x + v1[j].y * ql[j].y + v1[j].z * ql[j].z + v1[j].w * ql[j].w;
            sq1 += v1[j].x * v1[j].x + v1[j].y * v1[j].y + v1[j].z * v1[j].z + v1[j].w * v1[j].w;
        }
        d0 = rowsum16(d0);  sq0 = rowsum16(sq0);
        d1 = rowsum16(d1);  sq1 = rowsum16(sq1);
        if (c == 0) {
            const float en0 = fmaxf(sqrtf(sq0), EPS);
            const unsigned u0 = mono((d0 / (en0 * qn)) * boost[rl0]);
            keys_out[base + rl0] = u0;
            atomicAdd(&hist[u0 >> BIN_SHIFT], 1u);
            const float en1 = fmaxf(sqrtf(sq1), EPS);
            const unsigned u1 = mono((d1 / (en1 * qn)) * boost[rl1]);
            keys_out[base + rl1] = u1;
            atomicAdd(&hist[u1 >> BIN_SHIFT], 1u);
        }
    }
    __syncthreads();
    for (int j = tid; j < NBINS; j += 256) {
        const unsigned h = hist[j];
        if (h) atomicAdd(&ghist[j], h);
    }
}

// ---- B: find largest bin b with suffix-count(b) >= k; threshold = b << BIN_SHIFT ----
__global__ __launch_bounds__(256) void scan_kernel(
    const unsigned* __restrict__ ghist, unsigned* __restrict__ thresh, int k) {
    __shared__ unsigned partial[256];
    __shared__ unsigned suffix[256];
    const int tid = threadIdx.x;
    unsigned bins[16];
    unsigned p = 0;
#pragma unroll
    for (int j = 0; j < 16; ++j) { bins[j] = ghist[tid * 16 + j]; p += bins[j]; }
    partial[tid] = p;
    __syncthreads();
    if (tid == 0) {
        unsigned run = 0;
        for (int t = 255; t >= 0; --t) { suffix[t] = run; run += partial[t]; }
    }
    __syncthreads();
    const unsigned above = suffix[tid];
    if (above < (unsigned)k && above + p >= (unsigned)k) {  // unique crossing chunk
        unsigned run = above;
        int b = tid * 16;
        for (int j = 15; j >= 0; --j) {
            run += bins[j];
            if (run >= (unsigned)k) { b = tid * 16 + j; break; }
        }
        thresh[0] = ((unsigned)b) << BIN_SHIFT;
    }
}

// ---- C: compact candidates >= threshold (order-invariant downstream) ----
__global__ __launch_bounds__(256) void compact_kernel(
    const unsigned* __restrict__ keys, const unsigned* __restrict__ thresh,
    unsigned* __restrict__ counter, unsigned long long* __restrict__ cand) {
    const unsigned T = thresh[0];
    const int i0 = (blockIdx.x * 256 + threadIdx.x) * 4;
    const uint4 kv = *(const uint4*)(keys + i0);
#pragma unroll
    for (int j = 0; j < 4; ++j) {
        const unsigned kj = j == 0 ? kv.x : j == 1 ? kv.y : j == 2 ? kv.z : kv.w;
        if (kj >= T) {
            const unsigned p = atomicAdd(counter, 1u);
            if (p < CAP)
                cand[p] = ((unsigned long long)kj << 32) |
                          (unsigned long long)(0xFFFFFFFFu - (unsigned)(i0 + j));
        }
    }
}

// ---- D: rank-based exact top-k (no serial loop) ----
// Keys unique -> ranks unique -> each of the k output slots written exactly once.
__global__ __launch_bounds__(256) void final_select_kernel(
    const unsigned long long* __restrict__ cand, const unsigned* __restrict__ counter,
    float* __restrict__ out, int k) {
    __shared__ unsigned long long skeys[CAP];
    const int tid = threadIdx.x;
    const int count = min((int)counter[0], CAP);
    for (int j = tid; j < count; j += 256) skeys[j] = cand[j];
    __syncthreads();
    for (int j = tid; j < count; j += 256) {
        const unsigned long long kj = skeys[j];
        int r = 0;
        for (int i = 0; i < count; ++i) r += (skeys[i] > kj);  // broadcast LDS reads
        if (r < k) {
            out[r]     = unmono((unsigned)(kj >> 32));
            out[k + r] = (float)(0xFFFFFFFFu - (unsigned)(kj & 0xFFFFFFFFu));
        }
    }
}

extern "C" void kernel_launch(void* const* d_in, const int* in_sizes, int n_in,
                              void* d_out, int out_size, void* d_ws, size_t ws_size,
                              hipStream_t stream) {
    const float* q   = (const float*)d_in[0];   // [256]
    const float* emb = (const float*)d_in[1];   // [N,256]
    const float* rep = (const float*)d_in[2];   // [N]
    const int N = in_sizes[2];                  // 1048576
    const int k = out_size / 2;                 // 64

    // ws layout: keys u32[N] | ghist u32[NBINS] | thresh u32 | counter u32 | cand u64[CAP]
    unsigned* keys    = (unsigned*)d_ws;
    unsigned* ghist   = keys + N;
    unsigned* thresh  = ghist + NBINS;
    unsigned* counter = thresh + 1;
    unsigned long long* cand = (unsigned long long*)(counter + 1);  // 8B-aligned

    // zero histogram + threshold + counter each call (ws not re-poisoned between replays)
    (void)hipMemsetAsync(ghist, 0, (NBINS + 2) * sizeof(unsigned), stream);

    score_hist_kernel<<<NBLOCKS_A, 256, 0, stream>>>(
        (const f4*)q, (const f4*)emb, rep, keys, ghist, N / NBLOCKS_A);
    scan_kernel<<<1, 256, 0, stream>>>(ghist, thresh, k);
    compact_kernel<<<N / 1024, 256, 0, stream>>>(keys, thresh, counter, cand);
    final_select_kernel<<<1, 256, 0, stream>>>(cand, counter, (float*)d_out, k);
}

// Round 10
// 195.461 us; speedup vs baseline: 1.1497x; 1.0125x over previous
//
#include <hip/hip_runtime.h>
#include <math.h>

#define EPS 1e-8f
#define NBINS 4096
#define BIN_SHIFT 20    // 32 - log2(NBINS)
#define CAP 4096        // candidate buffer capacity (expected ~100-400 used)
#define NBLOCKS_A 2048  // 8 blocks/CU on 256 CUs

typedef float f4 __attribute__((ext_vector_type(4)));

// monotonic map: float -> u32 preserving order (no NaNs in this problem)
__device__ __forceinline__ unsigned mono(float v) {
    unsigned u = __float_as_uint(v);
    return (u & 0x80000000u) ? ~u : (u | 0x80000000u);
}
__device__ __forceinline__ float unmono(unsigned u) {
    return __uint_as_float((u & 0x80000000u) ? (u & 0x7FFFFFFFu) : ~u);
}

// 16-lane (DPP row) sum: ror8, ror4, quad xor2, quad xor1 — pure VALU, no DS pipe.
__device__ __forceinline__ float rowsum16(float x) {
    x += __int_as_float(__builtin_amdgcn_update_dpp(0, __float_as_int(x), 0x128, 0xF, 0xF, true)); // row_ror:8
    x += __int_as_float(__builtin_amdgcn_update_dpp(0, __float_as_int(x), 0x124, 0xF, 0xF, true)); // row_ror:4
    x += __int_as_float(__builtin_amdgcn_update_dpp(0, __float_as_int(x), 0x04E, 0xF, 0xF, true)); // quad_perm xor2
    x += __int_as_float(__builtin_amdgcn_update_dpp(0, __float_as_int(x), 0x0B1, 0xF, 0xF, true)); // quad_perm xor1
    return x;
}

// ---- A: score all rows, write monotonic keys, build global histogram ----
// R9 structure (197.9us): 16 lanes/row, 2x unroll, nontemporal emb loads.
__global__ __launch_bounds__(256, 8) void score_hist_kernel(
    const f4* __restrict__ q4, const f4* __restrict__ emb,
    const float* __restrict__ rep, unsigned* __restrict__ keys_out,
    unsigned* __restrict__ ghist, int rows_per_block) {
    __shared__ unsigned hist[NBINS];
    __shared__ float boost[512];
    const int tid = threadIdx.x;
    for (int j = tid; j < NBINS; j += 256) hist[j] = 0;

    const int lane = tid & 63;
    const int w = tid >> 6;
    const int c = lane & 15;    // column group within row
    const int sub = lane >> 4;  // which of the wave's 4 rows
    const int base = blockIdx.x * rows_per_block;

    // precompute reputation boost for this block's 512 rows (coalesced, nt: zero reuse)
    {
        const float r0 = __builtin_nontemporal_load(rep + base + tid);
        const float r1 = __builtin_nontemporal_load(rep + base + 256 + tid);
        boost[tid]       = 1.0f + 0.1f * tanhf(0.5f * r0);
        boost[tid + 256] = 1.0f + 0.1f * tanhf(0.5f * r1);
    }

    f4 ql[4];
    float qsq = 0.f;
#pragma unroll
    for (int j = 0; j < 4; ++j) {
        ql[j] = q4[c + 16 * j];
        qsq += ql[j].x * ql[j].x + ql[j].y * ql[j].y + ql[j].z * ql[j].z + ql[j].w * ql[j].w;
    }
    qsq = rowsum16(qsq);
    const float qn = fmaxf(sqrtf(qsq), EPS);

    __syncthreads();  // hist zeroed, boost ready

    const int iters = rows_per_block >> 5;  // 32 rows per block-iteration (2x unroll)
    for (int it = 0; it < iters; ++it) {
        const int rl0 = (it << 5) + (w << 2) + sub;
        const int rl1 = rl0 + 16;
        const f4* rp0 = emb + (size_t)(base + rl0) * 64 + c;
        const f4* rp1 = emb + (size_t)(base + rl1) * 64 + c;
        f4 v0[4], v1[4];
#pragma unroll
        for (int j = 0; j < 4; ++j) v0[j] = __builtin_nontemporal_load(rp0 + 16 * j);
#pragma unroll
        for (int j = 0; j < 4; ++j) v1[j] = __builtin_nontemporal_load(rp1 + 16 * j);

        float d0 = 0.f, sq0 = 0.f, d1 = 0.f, sq1 = 0.f;
#pragma unroll
        for (int j = 0; j < 4; ++j) {
            d0  += v0[j].x * ql[j].x + v0[j].y * ql[j].y + v0[j].z * ql[j].z + v0[j].w * ql[j].w;
            sq0 += v0[j].x * v0[j].x + v0[j].y * v0[j].y + v0[j].z * v0[j].z + v0[j].w * v0[j].w;
        }
#pragma unroll
        for (int j = 0; j < 4; ++j) {
            d1  += v1[j].x * ql[j].x + v1[j].y * ql[j].y + v1[j].z * ql[j].z + v1[j].w * ql[j].w;
            sq1 += v1[j].x * v1[j].x + v1[j].y * v1[j].y + v1[j].z * v1[j].z + v1[j].w * v1[j].w;
        }
        d0 = rowsum16(d0);  sq0 = rowsum16(sq0);
        d1 = rowsum16(d1);  sq1 = rowsum16(sq1);
        if (c == 0) {
            const float en0 = fmaxf(sqrtf(sq0), EPS);
            const unsigned u0 = mono((d0 / (en0 * qn)) * boost[rl0]);
            keys_out[base + rl0] = u0;
            atomicAdd(&hist[u0 >> BIN_SHIFT], 1u);
            const float en1 = fmaxf(sqrtf(sq1), EPS);
            const unsigned u1 = mono((d1 / (en1 * qn)) * boost[rl1]);
            keys_out[base + rl1] = u1;
            atomicAdd(&hist[u1 >> BIN_SHIFT], 1u);
        }
    }
    __syncthreads();
    for (int j = tid; j < NBINS; j += 256) {
        const unsigned h = hist[j];
        if (h) atomicAdd(&ghist[j], h);
    }
}

// ---- B+C fused: every block computes the threshold from ghist (pure function,
// bit-identical across blocks), then compacts its keys slice. Removes the
// separate 1-block scan dispatch. Suffix-scan: Hillis-Steele over 256 chunk
// partials (8 steps x 2 barriers), then a 16-bin walk in the crossing chunk.
__global__ __launch_bounds__(256) void compact_kernel(
    const unsigned* __restrict__ keys, const unsigned* __restrict__ ghist,
    unsigned* __restrict__ counter, unsigned long long* __restrict__ cand, int k) {
    __shared__ unsigned sc[256];
    __shared__ unsigned thr;
    const int tid = threadIdx.x;

    unsigned bins[16];
    unsigned p = 0;
#pragma unroll
    for (int j = 0; j < 16; ++j) { bins[j] = ghist[tid * 16 + j]; p += bins[j]; }
    unsigned s = p;
    sc[tid] = s;
    __syncthreads();
#pragma unroll
    for (int off = 1; off < 256; off <<= 1) {
        const unsigned add = (tid + off < 256) ? sc[tid + off] : 0u;
        __syncthreads();
        s += add;
        sc[tid] = s;
        __syncthreads();
    }
    // s = inclusive suffix sum of chunk partials; above = strictly-above count
    const unsigned above = s - p;
    if (above < (unsigned)k && s >= (unsigned)k) {  // unique crossing chunk
        unsigned run = above;
        int b = tid * 16;
        for (int j = 15; j >= 0; --j) {
            run += bins[j];
            if (run >= (unsigned)k) { b = tid * 16 + j; break; }
        }
        thr = ((unsigned)b) << BIN_SHIFT;
    }
    __syncthreads();
    const unsigned T = thr;

    const int i0 = (blockIdx.x * 256 + tid) * 4;
    const uint4 kv = *(const uint4*)(keys + i0);
#pragma unroll
    for (int j = 0; j < 4; ++j) {
        const unsigned kj = j == 0 ? kv.x : j == 1 ? kv.y : j == 2 ? kv.z : kv.w;
        if (kj >= T) {
            const unsigned pos = atomicAdd(counter, 1u);
            if (pos < CAP)
                cand[pos] = ((unsigned long long)kj << 32) |
                            (unsigned long long)(0xFFFFFFFFu - (unsigned)(i0 + j));
        }
    }
}

// ---- D: rank-based exact top-k (no serial loop) ----
// Keys unique -> ranks unique -> each of the k output slots written exactly once.
__global__ __launch_bounds__(256) void final_select_kernel(
    const unsigned long long* __restrict__ cand, const unsigned* __restrict__ counter,
    float* __restrict__ out, int k) {
    __shared__ unsigned long long skeys[CAP];
    const int tid = threadIdx.x;
    const int count = min((int)counter[0], CAP);
    for (int j = tid; j < count; j += 256) skeys[j] = cand[j];
    __syncthreads();
    for (int j = tid; j < count; j += 256) {
        const unsigned long long kj = skeys[j];
        int r = 0;
        for (int i = 0; i < count; ++i) r += (skeys[i] > kj);  // broadcast LDS reads
        if (r < k) {
            out[r]     = unmono((unsigned)(kj >> 32));
            out[k + r] = (float)(0xFFFFFFFFu - (unsigned)(kj & 0xFFFFFFFFu));
        }
    }
}

extern "C" void kernel_launch(void* const* d_in, const int* in_sizes, int n_in,
                              void* d_out, int out_size, void* d_ws, size_t ws_size,
                              hipStream_t stream) {
    const float* q   = (const float*)d_in[0];   // [256]
    const float* emb = (const float*)d_in[1];   // [N,256]
    const float* rep = (const float*)d_in[2];   // [N]
    const int N = in_sizes[2];                  // 1048576
    const int k = out_size / 2;                 // 64

    // ws layout: keys u32[N] | ghist u32[NBINS] | counter u32 | pad u32 | cand u64[CAP]
    unsigned* keys    = (unsigned*)d_ws;
    unsigned* ghist   = keys + N;
    unsigned* counter = ghist + NBINS;
    unsigned long long* cand = (unsigned long long*)(counter + 2);  // 8B-aligned

    // zero histogram + counter each call (ws not re-poisoned between replays)
    (void)hipMemsetAsync(ghist, 0, (NBINS + 2) * sizeof(unsigned), stream);

    score_hist_kernel<<<NBLOCKS_A, 256, 0, stream>>>(
        (const f4*)q, (const f4*)emb, rep, keys, ghist, N / NBLOCKS_A);
    compact_kernel<<<N / 1024, 256, 0, stream>>>(keys, ghist, counter, cand, k);
    final_select_kernel<<<1, 256, 0, stream>>>(cand, counter, (float*)d_out, k);
}